// Round 5
// baseline (39.371 us; speedup 1.0000x reference)
//
#include <hip/hip_runtime.h>

// ---------------- problem constants ----------------
#define NC    2
#define NB    9
#define NNODE 820
#define NL    3
#define NK    17
#define G     4          // nodes per block
#define NGB   205        // 820 / G

#define EPSF     1e-30f
// scale constant: C = sqrt(log2(e)/2); exp(-d^2/2) == exp2(-(d*C)^2)
#define C_SCF    0.84932178f
// ISQ2PI / C   (pdf normalization when one 1/sigma factor is C-scaled)
#define KLPN     0.46971920f
// I2PI / C^2   (normalization when two 1/sigma factors are C-scaled)
#define KE       0.22063560f

// output layout (flat f32 offsets, concatenated in reference return order)
#define OFF_XN    0LL
#define OFF_XE    752760LL
#define OFF_LPN   26315388LL
#define OFF_LPE   27068148LL
#define OFF_ALPHA 39849462LL
#define OFF_O1    39849516LL
#define OFF_O2    39893742LL

// ---------------- compile-time Gauss-Hermite nodes (n=17) ----------------
constexpr double csqrt(double v) {
    if (v <= 0.0) return 0.0;
    double y = v > 1.0 ? v : 1.0;
    for (int i = 0; i < 80; ++i) y = 0.5 * (y + v / y);
    return y;
}

struct HNodesF { float x[NK]; };

constexpr HNodesF compute_nodes() {
    const int n = NK;
    const double PIM4 = 0.7511255444649425;   // pi^{-1/4}
    double c1[NK + 1] = {}, c2[NK + 1] = {};
    for (int j = 1; j <= n; ++j) {
        c1[j] = csqrt(2.0 / (double)j);
        c2[j] = csqrt(((double)j - 1.0) / (double)j);
    }
    const double PPC = csqrt(2.0 * (double)n);
    double xr[9] = {};
    double z = 0.0;
    for (int i = 0; i < 9; ++i) {
        if (i == 0)      z = csqrt(2.0 * n + 1.0) - 1.85575 * 0.552905;   // 35^-0.16667
        else if (i == 1) z -= 1.14 * 3.34327 / z;                          // 17^0.426
        else if (i == 2) z = 1.86 * z - 0.86 * xr[0];
        else if (i == 3) z = 1.91 * z - 0.91 * xr[1];
        else             z = 2.0 * z - xr[i - 2];
        for (int it = 0; it < 24; ++it) {
            double p1 = PIM4, p2 = 0.0;
            for (int j = 1; j <= n; ++j) {
                double p3 = p2;
                p2 = p1;
                p1 = z * c1[j] * p2 - c2[j] * p3;
            }
            double pp = PPC * p2;
            double z1 = z;
            z = z1 - p1 / pp;
            double d = z - z1; if (d < 0.0) d = -d;
            if (d <= 3.0e-14) break;
        }
        xr[i] = z;
    }
    HNodesF f{};
    for (int i = 0; i < 9; ++i) {
        f.x[16 - i] = (float)xr[i];
        f.x[i]      = (float)(-xr[i]);
    }
    return f;
}

// (xi*sqrt2, xj*sqrt2) table for q in [0,289): xi = x[q%17], xj = x[q/17]
struct TabF { float v[289 * 2]; };
constexpr TabF make_tab() {
    HNodesF h = compute_nodes();
    TabF t{};
    for (int q = 0; q < 289; ++q) {
        t.v[2 * q]     = (float)((double)h.x[q % 17] * 1.4142135623730951);
        t.v[2 * q + 1] = (float)((double)h.x[q / 17] * 1.4142135623730951);
    }
    return t;
}
constexpr TabF TABC = make_tab();

__device__ __forceinline__ int idOf(int n) {
    if (n < 729) { return 729 + (n / 81) * 9 + (n % 27) / 3; }
    if (n < 810) { int m = n - 729; return 810 + (m / 27) * 3 + (m % 9) / 3; }
    return 819;
}

__device__ __forceinline__ float rcpf(float x) { return __builtin_amdgcn_rcpf(x); }

// ---------------- single fused kernel ----------------
// grid = (205, 18); block (g, cb) handles nodes n0..n0+3 of batch-slice cb.
__global__ __launch_bounds__(256) void fused_kernel(const float* __restrict__ mu,
                                                    const float* __restrict__ sg,
                                                    const float* __restrict__ w,
                                                    float* __restrict__ out) {
    const int g   = blockIdx.x;           // 0..204
    const int cb  = blockIdx.y;           // 0..17
    const int b   = cb % NB;
    const int n0  = g * G;
    const int tid = threadIdx.x;

    __shared__ float2 tab[289];
    {
        const float2* tc = (const float2*)TABC.v;
        tab[tid] = tc[tid];
        if (tid < 33) tab[256 + tid] = tc[256 + tid];
    }

    // softmax alphas (uniform across block)
    const float* wB = w + cb * 3;
    float w0 = wB[0], w1 = wB[1], w2 = wB[2];
    float wm = fmaxf(w0, fmaxf(w1, w2));
    float e0 = __expf(w0 - wm), e1 = __expf(w1 - wm), e2 = __expf(w2 - wm);
    float ainv = 1.0f / (e0 + e1 + e2);
    float a0 = e0 * ainv, a1 = e1 * ainv, a2 = e2 * ainv;

    const size_t cbase = (size_t)cb * NNODE;

    __syncthreads();

    // ---- xn + lpn: threads 0..203 handle (nn, l1, k) = t/51, (t%51)/17, t%17 ----
    if (tid < 204) {
        int nn = tid / 51;
        int r  = tid - 51 * nn;
        int l1 = r / 17;
        int k  = r - 17 * l1;
        int n  = n0 + nn;
        size_t mb = (cbase + n) * 3;
        float ul = mu[mb + l1], sl = sg[mb + l1];
        float xn = fmaf(tab[k].x, sl, ul);      // tab[k].x = node_k * sqrt2
        out[OFF_XN + (cbase + n0) * 51 + tid] = xn;

        float lp = 0.0f;
        if (!(b >= 1 && n < 729)) {
            float ua = mu[mb], ub = mu[mb + 1], uc = mu[mb + 2];
            float ia = C_SCF * rcpf(sg[mb]);
            float ib = C_SCF * rcpf(sg[mb + 1]);
            float ic = C_SCF * rcpf(sg[mb + 2]);
            float d0 = (xn - ua) * ia;
            float d1 = (xn - ub) * ib;
            float d2 = (xn - uc) * ic;
            float sum = a0 * ia * exp2f(-(d0 * d0))
                      + a1 * ib * exp2f(-(d1 * d1))
                      + a2 * ic * exp2f(-(d2 * d2));
            lp = __logf(sum * KLPN + EPSF);
        }
        out[OFF_LPN + (cbase + n0) * 51 + tid] = lp;
    } else if (tid < 216) {           // o1: 4 nodes x 3
        int t = tid - 204; int nn = t / 3, c = t - 3 * nn; int n = n0 + nn;
        if (n < 819) out[OFF_O1 + ((size_t)cb * 819 + n) * 3 + c] = sg[(cbase + n) * 3 + c];
    } else if (tid < 228) {           // o2: 4 nodes x 3 (gathered)
        int t = tid - 216; int nn = t / 3, c = t - 3 * nn; int n = n0 + nn;
        if (n < 819) out[OFF_O2 + ((size_t)cb * 819 + n) * 3 + c] = sg[(cbase + idOf(n)) * 3 + c];
    }

    // ---- alpha (block (0,0), threads 0..53 as extra work) ----
    if (g == 0 && cb == 0 && tid < 54) {
        int cb2 = tid / 3, l = tid - 3 * cb2;
        const float* wB2 = w + cb2 * 3;
        float v0 = wB2[0], v1 = wB2[1], v2 = wB2[2];
        float vm = fmaxf(v0, fmaxf(v1, v2));
        float f0 = __expf(v0 - vm), f1 = __expf(v1 - vm), f2 = __expf(v2 - vm);
        float finv = 1.0f / (f0 + f1 + f2);
        float fl = (l == 0) ? f0 : ((l == 1) ? f1 : f2);
        out[OFF_ALPHA + tid] = fl * finv;
    }

    // ---- edge: xe + lpe, 12 unrolled (nn,l1) sections, q = tid + tails ----
    // Affine fold: (x2 - u2m)*i2m = fma(tab_y, s2l*i2m, (u2l-u2m)*i2m) — the
    // standardized distances are one fma each off the LDS table value.
    const int wv = tid >> 6, ln = tid & 63;
    const size_t ecb = (size_t)cb * 819;

#pragma unroll
    for (int nn = 0; nn < G; ++nn) {
        int n = n0 + nn;
        if (n >= 819) continue;
        int idn = idOf(n);
        size_t mb1 = (cbase + n) * 3, mb2 = (cbase + (size_t)idn) * 3;
        float u1a = mu[mb1], u1b = mu[mb1 + 1], u1c = mu[mb1 + 2];
        float s1a = sg[mb1], s1b = sg[mb1 + 1], s1c = sg[mb1 + 2];
        float u2a = mu[mb2], u2b = mu[mb2 + 1], u2c = mu[mb2 + 2];
        float s2a = sg[mb2], s2b = sg[mb2 + 1], s2c = sg[mb2 + 2];
        float i2a = C_SCF * rcpf(s2a), i2b = C_SCF * rcpf(s2b), i2c = C_SCF * rcpf(s2c);

        const bool mk = (b >= 1) && (n < 729);
        float i1a = 0.f, i1b = 0.f, i1c = 0.f, ca, cbv, cc;
        if (mk) {
            ca  = a0 * i2a * KLPN;
            cbv = a1 * i2b * KLPN;
            cc  = a2 * i2c * KLPN;
        } else {
            i1a = C_SCF * rcpf(s1a); i1b = C_SCF * rcpf(s1b); i1c = C_SCF * rcpf(s1c);
            ca  = a0 * i1a * i2a * KE;
            cbv = a1 * i1b * i2b * KE;
            cc  = a2 * i1c * i2c * KE;
        }

        float2* xp0 = reinterpret_cast<float2*>(out + OFF_XE) + (ecb + n) * 867;
        float*  lp0 = out + OFF_LPE + (ecb + n) * 867;

#pragma unroll
        for (int l1 = 0; l1 < 3; ++l1) {
            float u1l = (l1 == 0) ? u1a : ((l1 == 1) ? u1b : u1c);
            float s1l = (l1 == 0) ? s1a : ((l1 == 1) ? s1b : s1c);
            float u2l = (l1 == 0) ? u2a : ((l1 == 1) ? u2b : u2c);
            float s2l = (l1 == 0) ? s2a : ((l1 == 1) ? s2b : s2c);
            float2* xp = xp0 + l1 * 289;
            float*  lp = lp0 + l1 * 289;

            // per-section affine coefficients (amortized over 289 elements)
            float Sd0 = s2l * i2a, Ud0 = (u2l - u2a) * i2a;
            float Sd1 = s2l * i2b, Ud1 = (u2l - u2b) * i2b;
            float Sd2 = s2l * i2c, Ud2 = (u2l - u2c) * i2c;
            float Sf0 = 0.f, Uf0 = 0.f, Sf1 = 0.f, Uf1 = 0.f, Sf2 = 0.f, Uf2 = 0.f;
            if (!mk) {
                Sf0 = s1l * i1a; Uf0 = (u1l - u1a) * i1a;
                Sf1 = s1l * i1b; Uf1 = (u1l - u1b) * i1b;
                Sf2 = s1l * i1c; Uf2 = (u1l - u1c) * i1c;
            }

            auto body = [&](int q) {
                float2 tv = tab[q];
                float x1 = fmaf(tv.x, s1l, u1l);
                float x2 = fmaf(tv.y, s2l, u2l);
                xp[q] = make_float2(x1, x2);
                float d0 = fmaf(tv.y, Sd0, Ud0);
                float d1 = fmaf(tv.y, Sd1, Ud1);
                float d2 = fmaf(tv.y, Sd2, Ud2);
                float t0 = d0 * d0, t1 = d1 * d1, t2 = d2 * d2;
                if (!mk) {
                    float f0v = fmaf(tv.x, Sf0, Uf0); t0 = fmaf(f0v, f0v, t0);
                    float f1v = fmaf(tv.x, Sf1, Uf1); t1 = fmaf(f1v, f1v, t1);
                    float f2v = fmaf(tv.x, Sf2, Uf2); t2 = fmaf(f2v, f2v, t2);
                }
                float sum = fmaf(cc, exp2f(-t2), fmaf(cbv, exp2f(-t1), ca * exp2f(-t0)));
                lp[q] = __logf(sum + EPSF);
            };

            body(tid);                                        // q in [0,256)
            const int sec = nn * 3 + l1;
            if (wv == (sec & 3) && ln < 33) body(256 + ln);   // q in [256,289)
        }
    }
}

extern "C" void kernel_launch(void* const* d_in, const int* in_sizes, int n_in,
                              void* d_out, int out_size, void* d_ws, size_t ws_size,
                              hipStream_t stream) {
    const float* mu    = (const float*)d_in[0];
    const float* sigma = (const float*)d_in[1];
    const float* w     = (const float*)d_in[2];
    float* out = (float*)d_out;

    hipLaunchKernelGGL(fused_kernel, dim3(NGB, NC * NB), dim3(256), 0, stream,
                       mu, sigma, w, out);
}

// Round 6
// 35.131 us; speedup vs baseline: 1.1207x; 1.1207x over previous
//
#include <hip/hip_runtime.h>

// ---------------- problem constants ----------------
#define NC    2
#define NB    9
#define NNODE 820
#define NL    3
#define NK    17
#define G     4          // nodes per block
#define NGB   205        // 820 / G

#define EPSF     1e-30f
// scale constant: C = sqrt(log2(e)/2); exp(-d^2/2) == exp2(-(d*C)^2)
#define C_SCF    0.84932178f
// ISQ2PI / C   (pdf normalization when one 1/sigma factor is C-scaled)
#define KLPN     0.46971920f
// I2PI / C^2   (normalization when two 1/sigma factors are C-scaled)
#define KE       0.22063560f

// output layout (flat f32 offsets, concatenated in reference return order)
#define OFF_XN    0LL
#define OFF_XE    752760LL
#define OFF_LPN   26315388LL
#define OFF_LPE   27068148LL
#define OFF_ALPHA 39849462LL
#define OFF_O1    39849516LL
#define OFF_O2    39893742LL

// ---------------- compile-time Gauss-Hermite nodes (n=17) ----------------
constexpr double csqrt(double v) {
    if (v <= 0.0) return 0.0;
    double y = v > 1.0 ? v : 1.0;
    for (int i = 0; i < 80; ++i) y = 0.5 * (y + v / y);
    return y;
}

struct HNodesF { float x[NK]; };

constexpr HNodesF compute_nodes() {
    const int n = NK;
    const double PIM4 = 0.7511255444649425;   // pi^{-1/4}
    double c1[NK + 1] = {}, c2[NK + 1] = {};
    for (int j = 1; j <= n; ++j) {
        c1[j] = csqrt(2.0 / (double)j);
        c2[j] = csqrt(((double)j - 1.0) / (double)j);
    }
    const double PPC = csqrt(2.0 * (double)n);
    double xr[9] = {};
    double z = 0.0;
    for (int i = 0; i < 9; ++i) {
        if (i == 0)      z = csqrt(2.0 * n + 1.0) - 1.85575 * 0.552905;   // 35^-0.16667
        else if (i == 1) z -= 1.14 * 3.34327 / z;                          // 17^0.426
        else if (i == 2) z = 1.86 * z - 0.86 * xr[0];
        else if (i == 3) z = 1.91 * z - 0.91 * xr[1];
        else             z = 2.0 * z - xr[i - 2];
        for (int it = 0; it < 24; ++it) {
            double p1 = PIM4, p2 = 0.0;
            for (int j = 1; j <= n; ++j) {
                double p3 = p2;
                p2 = p1;
                p1 = z * c1[j] * p2 - c2[j] * p3;
            }
            double pp = PPC * p2;
            double z1 = z;
            z = z1 - p1 / pp;
            double d = z - z1; if (d < 0.0) d = -d;
            if (d <= 3.0e-14) break;
        }
        xr[i] = z;
    }
    HNodesF f{};
    for (int i = 0; i < 9; ++i) {
        f.x[16 - i] = (float)xr[i];
        f.x[i]      = (float)(-xr[i]);
    }
    return f;
}

// (xi*sqrt2, xj*sqrt2) table for q in [0,289): xi = x[q%17], xj = x[q/17]
struct TabF { float v[289 * 2]; };
constexpr TabF make_tab() {
    HNodesF h = compute_nodes();
    TabF t{};
    for (int q = 0; q < 289; ++q) {
        t.v[2 * q]     = (float)((double)h.x[q % 17] * 1.4142135623730951);
        t.v[2 * q + 1] = (float)((double)h.x[q / 17] * 1.4142135623730951);
    }
    return t;
}
constexpr TabF TABC = make_tab();

__device__ __forceinline__ int idOf(int n) {
    if (n < 729) { return 729 + (n / 81) * 9 + (n % 27) / 3; }
    if (n < 810) { int m = n - 729; return 810 + (m / 27) * 3 + (m % 9) / 3; }
    return 819;
}

__device__ __forceinline__ float rcpf(float x) { return __builtin_amdgcn_rcpf(x); }

// ---------------- single fused kernel ----------------
// grid = (205, 18); block (g, cb) handles nodes n0..n0+3 of batch-slice cb.
// nn loop deliberately NOT unrolled: unrolling 4 nodes multiplies the live
// register set (~x4) with zero arithmetic saving -> occupancy loss (R5 lesson).
__global__ __launch_bounds__(256, 4) void fused_kernel(const float* __restrict__ mu,
                                                       const float* __restrict__ sg,
                                                       const float* __restrict__ w,
                                                       float* __restrict__ out) {
    const int g   = blockIdx.x;           // 0..204
    const int cb  = blockIdx.y;           // 0..17
    const int b   = cb % NB;
    const int n0  = g * G;
    const int tid = threadIdx.x;

    __shared__ float2 tab[289];
    {
        const float2* tc = (const float2*)TABC.v;
        tab[tid] = tc[tid];
        if (tid < 33) tab[256 + tid] = tc[256 + tid];
    }

    // softmax alphas (uniform across block)
    const float* wB = w + cb * 3;
    float w0 = wB[0], w1 = wB[1], w2 = wB[2];
    float wm = fmaxf(w0, fmaxf(w1, w2));
    float e0 = __expf(w0 - wm), e1 = __expf(w1 - wm), e2 = __expf(w2 - wm);
    float ainv = 1.0f / (e0 + e1 + e2);
    float a0 = e0 * ainv, a1 = e1 * ainv, a2 = e2 * ainv;

    const size_t cbase = (size_t)cb * NNODE;

    __syncthreads();

    // ---- xn + lpn: threads 0..203 handle (nn, l1, k) = t/51, (t%51)/17, t%17 ----
    if (tid < 204) {
        int nn = tid / 51;
        int r  = tid - 51 * nn;
        int l1 = r / 17;
        int k  = r - 17 * l1;
        int n  = n0 + nn;
        size_t mb = (cbase + n) * 3;
        float ul = mu[mb + l1], sl = sg[mb + l1];
        float xn = fmaf(tab[k].x, sl, ul);      // tab[k].x = node_k * sqrt2
        out[OFF_XN + (cbase + n0) * 51 + tid] = xn;

        float lp = 0.0f;
        if (!(b >= 1 && n < 729)) {
            float ua = mu[mb], ub = mu[mb + 1], uc = mu[mb + 2];
            float ia = C_SCF * rcpf(sg[mb]);
            float ib = C_SCF * rcpf(sg[mb + 1]);
            float ic = C_SCF * rcpf(sg[mb + 2]);
            float d0 = (xn - ua) * ia;
            float d1 = (xn - ub) * ib;
            float d2 = (xn - uc) * ic;
            float sum = a0 * ia * exp2f(-(d0 * d0))
                      + a1 * ib * exp2f(-(d1 * d1))
                      + a2 * ic * exp2f(-(d2 * d2));
            lp = __logf(sum * KLPN + EPSF);
        }
        out[OFF_LPN + (cbase + n0) * 51 + tid] = lp;
    } else if (tid < 216) {           // o1: 4 nodes x 3
        int t = tid - 204; int nn = t / 3, c = t - 3 * nn; int n = n0 + nn;
        if (n < 819) out[OFF_O1 + ((size_t)cb * 819 + n) * 3 + c] = sg[(cbase + n) * 3 + c];
    } else if (tid < 228) {           // o2: 4 nodes x 3 (gathered)
        int t = tid - 216; int nn = t / 3, c = t - 3 * nn; int n = n0 + nn;
        if (n < 819) out[OFF_O2 + ((size_t)cb * 819 + n) * 3 + c] = sg[(cbase + idOf(n)) * 3 + c];
    }

    // ---- alpha (block (0,0), threads 0..53 as extra work) ----
    if (g == 0 && cb == 0 && tid < 54) {
        int cb2 = tid / 3, l = tid - 3 * cb2;
        const float* wB2 = w + cb2 * 3;
        float v0 = wB2[0], v1 = wB2[1], v2 = wB2[2];
        float vm = fmaxf(v0, fmaxf(v1, v2));
        float f0 = __expf(v0 - vm), f1 = __expf(v1 - vm), f2 = __expf(v2 - vm);
        float finv = 1.0f / (f0 + f1 + f2);
        float fl = (l == 0) ? f0 : ((l == 1) ? f1 : f2);
        out[OFF_ALPHA + tid] = fl * finv;
    }

    // ---- edge: xe + lpe, (nn,l1) sections, q = tid + tails ----
    const int wv = tid >> 6, ln = tid & 63;
    const size_t ecb = (size_t)cb * 819;

#pragma unroll 1
    for (int nn = 0; nn < G; ++nn) {
        int n = n0 + nn;
        if (n >= 819) continue;
        int idn = idOf(n);
        size_t mb1 = (cbase + n) * 3, mb2 = (cbase + (size_t)idn) * 3;
        float u1a = mu[mb1], u1b = mu[mb1 + 1], u1c = mu[mb1 + 2];
        float s1a = sg[mb1], s1b = sg[mb1 + 1], s1c = sg[mb1 + 2];
        float u2a = mu[mb2], u2b = mu[mb2 + 1], u2c = mu[mb2 + 2];
        float s2a = sg[mb2], s2b = sg[mb2 + 1], s2c = sg[mb2 + 2];
        float i2a = C_SCF * rcpf(s2a), i2b = C_SCF * rcpf(s2b), i2c = C_SCF * rcpf(s2c);

        const bool mk = (b >= 1) && (n < 729);
        float i1a = 0.f, i1b = 0.f, i1c = 0.f, ca, cbv, cc;
        if (mk) {
            ca  = a0 * i2a * KLPN;
            cbv = a1 * i2b * KLPN;
            cc  = a2 * i2c * KLPN;
        } else {
            i1a = C_SCF * rcpf(s1a); i1b = C_SCF * rcpf(s1b); i1c = C_SCF * rcpf(s1c);
            ca  = a0 * i1a * i2a * KE;
            cbv = a1 * i1b * i2b * KE;
            cc  = a2 * i1c * i2c * KE;
        }

        float2* xp0 = reinterpret_cast<float2*>(out + OFF_XE) + (ecb + n) * 867;
        float*  lp0 = out + OFF_LPE + (ecb + n) * 867;

#pragma unroll
        for (int l1 = 0; l1 < 3; ++l1) {
            float u1l = (l1 == 0) ? u1a : ((l1 == 1) ? u1b : u1c);
            float s1l = (l1 == 0) ? s1a : ((l1 == 1) ? s1b : s1c);
            float u2l = (l1 == 0) ? u2a : ((l1 == 1) ? u2b : u2c);
            float s2l = (l1 == 0) ? s2a : ((l1 == 1) ? s2b : s2c);
            float2* xp = xp0 + l1 * 289;
            float*  lp = lp0 + l1 * 289;

            auto body = [&](int q) {
                float2 tv = tab[q];
                float x1 = fmaf(tv.x, s1l, u1l);
                float x2 = fmaf(tv.y, s2l, u2l);
                xp[q] = make_float2(x1, x2);
                float d0 = (x2 - u2a) * i2a;
                float d1 = (x2 - u2b) * i2b;
                float d2 = (x2 - u2c) * i2c;
                float t0 = d0 * d0, t1 = d1 * d1, t2 = d2 * d2;
                if (!mk) {
                    float f0v = (x1 - u1a) * i1a; t0 = fmaf(f0v, f0v, t0);
                    float f1v = (x1 - u1b) * i1b; t1 = fmaf(f1v, f1v, t1);
                    float f2v = (x1 - u1c) * i1c; t2 = fmaf(f2v, f2v, t2);
                }
                float sum = fmaf(cc, exp2f(-t2), fmaf(cbv, exp2f(-t1), ca * exp2f(-t0)));
                lp[q] = __logf(sum + EPSF);
            };

            body(tid);                                        // q in [0,256)
            const int sec = nn * 3 + l1;
            if (wv == (sec & 3) && ln < 33) body(256 + ln);   // q in [256,289)
        }
    }
}

extern "C" void kernel_launch(void* const* d_in, const int* in_sizes, int n_in,
                              void* d_out, int out_size, void* d_ws, size_t ws_size,
                              hipStream_t stream) {
    const float* mu    = (const float*)d_in[0];
    const float* sigma = (const float*)d_in[1];
    const float* w     = (const float*)d_in[2];
    float* out = (float*)d_out;

    hipLaunchKernelGGL(fused_kernel, dim3(NGB, NC * NB), dim3(256), 0, stream,
                       mu, sigma, w, out);
}

// Round 7
// 33.596 us; speedup vs baseline: 1.1719x; 1.0457x over previous
//
#include <hip/hip_runtime.h>

// ---------------- problem constants ----------------
#define NC    2
#define NB    9
#define NNODE 820
#define NL    3
#define NK    17
#define G     4          // nodes per block
#define NGB   205        // 820 / G

#define EPSF     1e-30f
// scale constant: C = sqrt(log2(e)/2); exp(-d^2/2) == exp2(-(d*C)^2)
#define C_SCF    0.84932178f
// ISQ2PI / C   (pdf normalization when one 1/sigma factor is C-scaled)
#define KLPN     0.46971920f
// I2PI / C^2   (normalization when two 1/sigma factors are C-scaled)
#define KE       0.22063560f

// output layout (flat f32 offsets, concatenated in reference return order)
#define OFF_XN    0LL
#define OFF_XE    752760LL
#define OFF_LPN   26315388LL
#define OFF_LPE   27068148LL
#define OFF_ALPHA 39849462LL
#define OFF_O1    39849516LL
#define OFF_O2    39893742LL

// ---------------- compile-time Gauss-Hermite nodes (n=17) ----------------
constexpr double csqrt(double v) {
    if (v <= 0.0) return 0.0;
    double y = v > 1.0 ? v : 1.0;
    for (int i = 0; i < 80; ++i) y = 0.5 * (y + v / y);
    return y;
}

struct HNodesF { float x[NK]; };

constexpr HNodesF compute_nodes() {
    const int n = NK;
    const double PIM4 = 0.7511255444649425;   // pi^{-1/4}
    double c1[NK + 1] = {}, c2[NK + 1] = {};
    for (int j = 1; j <= n; ++j) {
        c1[j] = csqrt(2.0 / (double)j);
        c2[j] = csqrt(((double)j - 1.0) / (double)j);
    }
    const double PPC = csqrt(2.0 * (double)n);
    double xr[9] = {};
    double z = 0.0;
    for (int i = 0; i < 9; ++i) {
        if (i == 0)      z = csqrt(2.0 * n + 1.0) - 1.85575 * 0.552905;   // 35^-0.16667
        else if (i == 1) z -= 1.14 * 3.34327 / z;                          // 17^0.426
        else if (i == 2) z = 1.86 * z - 0.86 * xr[0];
        else if (i == 3) z = 1.91 * z - 0.91 * xr[1];
        else             z = 2.0 * z - xr[i - 2];
        for (int it = 0; it < 24; ++it) {
            double p1 = PIM4, p2 = 0.0;
            for (int j = 1; j <= n; ++j) {
                double p3 = p2;
                p2 = p1;
                p1 = z * c1[j] * p2 - c2[j] * p3;
            }
            double pp = PPC * p2;
            double z1 = z;
            z = z1 - p1 / pp;
            double d = z - z1; if (d < 0.0) d = -d;
            if (d <= 3.0e-14) break;
        }
        xr[i] = z;
    }
    HNodesF f{};
    for (int i = 0; i < 9; ++i) {
        f.x[16 - i] = (float)xr[i];
        f.x[i]      = (float)(-xr[i]);
    }
    return f;
}

// (xi*sqrt2, xj*sqrt2) table for q in [0,289): xi = x[q%17], xj = x[q/17]
struct TabF { float v[289 * 2]; };
constexpr TabF make_tab() {
    HNodesF h = compute_nodes();
    TabF t{};
    for (int q = 0; q < 289; ++q) {
        t.v[2 * q]     = (float)((double)h.x[q % 17] * 1.4142135623730951);
        t.v[2 * q + 1] = (float)((double)h.x[q / 17] * 1.4142135623730951);
    }
    return t;
}
constexpr TabF TABC = make_tab();

__device__ __forceinline__ int idOf(int n) {
    if (n < 729) { return 729 + (n / 81) * 9 + (n % 27) / 3; }
    if (n < 810) { int m = n - 729; return 810 + (m / 27) * 3 + (m % 9) / 3; }
    return 819;
}

__device__ __forceinline__ float rcpf(float x) { return __builtin_amdgcn_rcpf(x); }

__device__ __forceinline__ float sel3(float a0, float a1, float a2, int i) {
    float r = a0;
    r = (i == 1) ? a1 : r;
    r = (i == 2) ? a2 : r;
    return r;
}

// ---------------- single fused kernel ----------------
// grid = (205, 18); block (g, cb) handles nodes n0..n0+3 of batch-slice cb.
// The mixture sum factorizes per section: exp(-(f^2+d^2)) = exp(-f^2)*exp(-d^2)
// where f depends only on i=q%17 and d only on j=q/17. Phase A precomputes
// Ei[sec][m][i], cEj[sec][m][j] (and, for masked sections where b1==1, the
// fully-reduced lpeJ[sec][j] INCLUDING the log) into LDS; the streaming loop
// is then ~8 (masked) / ~16 (unmasked) issue slots per element.
__global__ __launch_bounds__(256) void fused_kernel(const float* __restrict__ mu,
                                                    const float* __restrict__ sg,
                                                    const float* __restrict__ w,
                                                    float* __restrict__ out) {
    const int g   = blockIdx.x;           // 0..204
    const int cb  = blockIdx.y;           // 0..17
    const int b   = cb % NB;
    const int n0  = g * G;
    const int tid = threadIdx.x;

    __shared__ float2 tab[289];
    __shared__ float  params[48];         // [nn][12]: mu1[3],sg1[3],mu2[3],sg2[3]
    __shared__ float  sCEj[612];          // [sec][m][j]  sec=nn*3+l1
    __shared__ float  sEi [612];          // [sec][m][i]
    __shared__ float  sLpj[204];          // [sec][j]

    {
        const float2* tc = (const float2*)TABC.v;
        tab[tid] = tc[tid];
        if (tid < 33) tab[256 + tid] = tc[256 + tid];
    }

    const size_t cbase = (size_t)cb * NNODE;

    if (tid < 48) {
        int nn = tid / 12, r = tid - nn * 12;
        int n = n0 + nn;
        size_t b1a = (cbase + n) * 3;
        size_t b2a = (cbase + (size_t)idOf(n)) * 3;
        float v;
        if (r < 3)      v = mu[b1a + r];
        else if (r < 6) v = sg[b1a + r - 3];
        else if (r < 9) v = mu[b2a + r - 6];
        else            v = sg[b2a + r - 9];
        params[tid] = v;
    }

    // softmax alphas (uniform across block)
    const float* wB = w + cb * 3;
    float w0 = wB[0], w1 = wB[1], w2 = wB[2];
    float wm = fmaxf(w0, fmaxf(w1, w2));
    float e0 = __expf(w0 - wm), e1 = __expf(w1 - wm), e2 = __expf(w2 - wm);
    float ainv = 1.0f / (e0 + e1 + e2);
    float a0 = e0 * ainv, a1 = e1 * ainv, a2 = e2 * ainv;

    __syncthreads();

    // ---- xn + lpn: threads 0..203 handle (nn, l1, k) = t/51, (t%51)/17, t%17 ----
    if (tid < 204) {
        int nn = tid / 51;
        int r  = tid - 51 * nn;
        int l1 = r / 17;
        int k  = r - 17 * l1;
        int n  = n0 + nn;
        size_t mb = (cbase + n) * 3;
        float ul = mu[mb + l1], sl = sg[mb + l1];
        float xn = fmaf(tab[k].x, sl, ul);      // tab[k].x = node_k * sqrt2
        out[OFF_XN + (cbase + n0) * 51 + tid] = xn;

        float lp = 0.0f;
        if (!(b >= 1 && n < 729)) {
            float ua = mu[mb], ub = mu[mb + 1], uc = mu[mb + 2];
            float ia = C_SCF * rcpf(sg[mb]);
            float ib = C_SCF * rcpf(sg[mb + 1]);
            float ic = C_SCF * rcpf(sg[mb + 2]);
            float d0 = (xn - ua) * ia;
            float d1 = (xn - ub) * ib;
            float d2 = (xn - uc) * ic;
            float sum = a0 * ia * exp2f(-(d0 * d0))
                      + a1 * ib * exp2f(-(d1 * d1))
                      + a2 * ic * exp2f(-(d2 * d2));
            lp = __logf(sum * KLPN + EPSF);
        }
        out[OFF_LPN + (cbase + n0) * 51 + tid] = lp;
    } else if (tid < 216) {           // o1: 4 nodes x 3
        int t = tid - 204; int nn = t / 3, c = t - 3 * nn; int n = n0 + nn;
        if (n < 819) out[OFF_O1 + ((size_t)cb * 819 + n) * 3 + c] = sg[(cbase + n) * 3 + c];
    } else if (tid < 228) {           // o2: 4 nodes x 3 (gathered)
        int t = tid - 216; int nn = t / 3, c = t - 3 * nn; int n = n0 + nn;
        if (n < 819) out[OFF_O2 + ((size_t)cb * 819 + n) * 3 + c] = sg[(cbase + idOf(n)) * 3 + c];
    }

    // ---- alpha (block (0,0), threads 0..53 as extra work) ----
    if (g == 0 && cb == 0 && tid < 54) {
        int cb2 = tid / 3, l = tid - 3 * cb2;
        const float* wB2 = w + cb2 * 3;
        float v0 = wB2[0], v1 = wB2[1], v2 = wB2[2];
        float vm = fmaxf(v0, fmaxf(v1, v2));
        float f0 = __expf(v0 - vm), f1 = __expf(v1 - vm), f2 = __expf(v2 - vm);
        float finv = 1.0f / (f0 + f1 + f2);
        float fl = (l == 0) ? f0 : ((l == 1) ? f1 : f2);
        out[OFF_ALPHA + tid] = fl * finv;
    }

    // ---- phase A: per-section factor tables (612 values each) ----
    for (int v = tid; v < 612; v += 256) {
        int s  = v / 51, r = v - s * 51;
        int m  = r / 17, j = r - m * 17;
        int nn = s / 3,  l1 = s - nn * 3;
        int n  = n0 + nn;
        const float* P = params + nn * 12;
        float u1l = P[l1],     s1l = P[3 + l1];
        float u2l = P[6 + l1], s2l = P[9 + l1];
        float u1m = P[m],      s1m = P[3 + m];
        float u2m = P[6 + m],  s2m = P[9 + m];
        float i2m = C_SCF * rcpf(s2m);
        float i1m = C_SCF * rcpf(s1m);
        float am  = sel3(a0, a1, a2, m);
        bool  mk  = (b >= 1) && (n < 729);
        float cm  = mk ? (am * i2m * KLPN) : (am * i1m * i2m * KE);
        float xv  = tab[j].x;                // node_j * sqrt2
        float x2j = fmaf(xv, s2l, u2l);
        float d   = (x2j - u2m) * i2m;
        sCEj[v] = cm * exp2f(-(d * d));
        float x1i = fmaf(xv, s1l, u1l);
        float f   = (x1i - u1m) * i1m;
        sEi[v]  = exp2f(-(f * f));
    }
    __syncthreads();
    if (tid < 204) {
        int s = tid / 17, j = tid - s * 17;
        float sum = sCEj[s * 51 + j] + sCEj[s * 51 + 17 + j] + sCEj[s * 51 + 34 + j];
        sLpj[tid] = __logf(sum + EPSF);
    }
    __syncthreads();

    // ---- streaming: xe + lpe ----
    const int wv = tid >> 6, ln = tid & 63;
    const int j0 = tid / 17, i0 = tid - 17 * j0;
    const int qt = 256 + ln;
    const int jt = qt / 17, it = qt - 17 * jt;
    const size_t ecb = (size_t)cb * 819;

    for (int nn = 0; nn < G; ++nn) {
        int n = n0 + nn;
        if (n >= 819) continue;
        const bool mk = (b >= 1) && (n < 729);
        const float* P = params + nn * 12;
        float2* xp0 = reinterpret_cast<float2*>(out + OFF_XE) + (ecb + n) * 867;
        float*  lp0 = out + OFF_LPE + (ecb + n) * 867;

#pragma unroll
        for (int l1 = 0; l1 < 3; ++l1) {
            const int sec = nn * 3 + l1;
            float u1l = P[l1],     s1l = P[3 + l1];
            float u2l = P[6 + l1], s2l = P[9 + l1];
            float2* xp = xp0 + l1 * 289;
            float*  lp = lp0 + l1 * 289;
            const float* CE = sCEj + sec * 51;
            const float* EI = sEi  + sec * 51;
            const float* LJ = sLpj + sec * 17;

            auto body = [&](int q, int i, int j) {
                float2 tv = tab[q];
                float x1 = fmaf(tv.x, s1l, u1l);
                float x2 = fmaf(tv.y, s2l, u2l);
                xp[q] = make_float2(x1, x2);
                float lv;
                if (mk) {
                    lv = LJ[j];
                } else {
                    float sum = fmaf(EI[i], CE[j],
                                fmaf(EI[17 + i], CE[17 + j],
                                     EI[34 + i] * CE[34 + j]));
                    lv = __logf(sum + EPSF);
                }
                lp[q] = lv;
            };

            body(tid, i0, j0);                                // q in [0,256)
            if (wv == (sec & 3) && ln < 33) body(qt, it, jt); // q in [256,289)
        }
    }
}

extern "C" void kernel_launch(void* const* d_in, const int* in_sizes, int n_in,
                              void* d_out, int out_size, void* d_ws, size_t ws_size,
                              hipStream_t stream) {
    const float* mu    = (const float*)d_in[0];
    const float* sigma = (const float*)d_in[1];
    const float* w     = (const float*)d_in[2];
    float* out = (float*)d_out;

    hipLaunchKernelGGL(fused_kernel, dim3(NGB, NC * NB), dim3(256), 0, stream,
                       mu, sigma, w, out);
}